// Round 6
// baseline (237.695 us; speedup 1.0000x reference)
//
#include <hip/hip_runtime.h>
#include <stdint.h>

// InstanceHead on MI355X — f32/int32 inputs, f32 OUTPUT buffer.
// N=100000, M=256, B=8, L=128, D=64.  Batch ids are UNSORTED (jnp.sort axis=-1
// on (N,1) is a no-op) -> valid centroids scattered; batch-mask via w=0.
// R6: block-per-tile (grid 6250), attn weights materialized once in LDS
// (dist/sqrt/exp computed once per (row,col)), epilogue = MFMA + 2 muls,
// fully-coalesced float4 stores.  LDS 20.2 KB -> 8 blocks/CU (32 waves).

#define NN 100000
#define MM 256
#define LL 128
#define DD 64
#define NTILES (NN / 16)  // 6250, exact
#define WP 260            // w_s row stride (floats): rows 16B-aligned, 2-way banks max

typedef float f32x4 __attribute__((ext_vector_type(4)));
typedef __bf16 bf16x8 __attribute__((ext_vector_type(8)));

union U16x8 { uint4 u; bf16x8 v; unsigned short s[8]; };

static __device__ __forceinline__ unsigned short f2bf(float f) {
  union { float f; unsigned int i; } t; t.f = f;
  unsigned int x = t.i;
  x += 0x7fffu + ((x >> 16) & 1u);  // round-to-nearest-even
  return (unsigned short)(x >> 16);
}

// ---------------- prep: cen (bf16), W^T (bf16), centroid meta ----------------
__global__ __launch_bounds__(256) void prep_kernel(
    const int* __restrict__ cen_coords,
    const float* __restrict__ cen_feats,
    const float* __restrict__ conf,
    const float* __restrict__ W,
    const float* __restrict__ bvec,
    unsigned short* __restrict__ cen_ws,   // [256][64] bf16
    unsigned short* __restrict__ wt_ws,    // [64][128] bf16 (W transposed)
    float4* __restrict__ cmeta_ws)         // [256] {batch, x, y, z}
{
  int tid = threadIdx.x;
  if (blockIdx.x < 16) {
    int m = blockIdx.x * 16 + (tid >> 4);
    int c = tid & 15;
    float a0 = 0.f, a1 = 0.f, a2 = 0.f, a3 = 0.f;
    for (int l = 0; l < LL; l++) {
      float f = cen_feats[m * LL + l];
      const float* wr = W + l * DD + c;
      a0 += f * wr[0];  a1 += f * wr[16];
      a2 += f * wr[32]; a3 += f * wr[48];
    }
    float cf = conf[m];
    cen_ws[m * DD + c +  0] = f2bf(cf * (a0 + bvec[c +  0]));
    cen_ws[m * DD + c + 16] = f2bf(cf * (a1 + bvec[c + 16]));
    cen_ws[m * DD + c + 32] = f2bf(cf * (a2 + bvec[c + 32]));
    cen_ws[m * DD + c + 48] = f2bf(cf * (a3 + bvec[c + 48]));
  } else {
    for (int i = tid; i < LL * DD; i += 256) {
      int l = i >> 6, d = i & 63;
      wt_ws[d * LL + l] = f2bf(W[l * DD + d]);
    }
    {
      int4 cc = ((const int4*)cen_coords)[tid];  // tid < 256 == MM
      float4 f; f.x = (float)cc.x; f.y = (float)cc.y; f.z = (float)cc.z; f.w = (float)cc.w;
      cmeta_ws[tid] = f;
    }
  }
}

// ---------------- main: 1 block (4 waves) per 16-row tile ----------------
__global__ __launch_bounds__(256) void main_kernel(
    const int4* __restrict__ clu_coords4,
    const float* __restrict__ feats,
    const float* __restrict__ bvec,
    const unsigned short* __restrict__ cen_ws,
    const unsigned short* __restrict__ wt_ws,
    const float4* __restrict__ cmeta,
    float* __restrict__ out)
{
  __shared__ __align__(16) float w_s[16 * WP];            // 16640 B: attn, then out
  __shared__ __align__(16) unsigned short clu_s[16 * 72]; // 2304 B (+8 pad / row)
  __shared__ float part_s[16][16];                        // 1024 B reduce scratch
  __shared__ float dmin_s[16];
  __shared__ float invn_s[16];
  __shared__ float scale_s[16];                           // invden * inv_nrm

  int tid = threadIdx.x;
  int wave = tid >> 6, lane = tid & 63;
  int tile = blockIdx.x;
  int q = lane >> 4, c = lane & 15;

  if (wave == 0) {
    // ---- GEMM1 (wave0 only): clu = feats @ W (+b), A from global f32 feats
    f32x4 acc[4] = {{0,0,0,0},{0,0,0,0},{0,0,0,0},{0,0,0,0}};
    const float4* fb = (const float4*)(feats + (size_t)(tile * 16 + c) * LL);
    const uint4* wb = (const uint4*)wt_ws;
#pragma unroll
    for (int ks = 0; ks < 4; ks++) {
      float4 f0 = fb[ks * 8 + q * 2];
      float4 f1 = fb[ks * 8 + q * 2 + 1];
      U16x8 a;
      a.s[0] = f2bf(f0.x); a.s[1] = f2bf(f0.y); a.s[2] = f2bf(f0.z); a.s[3] = f2bf(f0.w);
      a.s[4] = f2bf(f1.x); a.s[5] = f2bf(f1.y); a.s[6] = f2bf(f1.z); a.s[7] = f2bf(f1.w);
#pragma unroll
      for (int nt = 0; nt < 4; nt++) {
        U16x8 b; b.u = wb[(nt * 16 + c) * 16 + ks * 4 + q];
        acc[nt] = __builtin_amdgcn_mfma_f32_16x16x32_bf16(a.v, b.v, acc[nt], 0, 0, 0);
      }
    }
#pragma unroll
    for (int nt = 0; nt < 4; nt++) {
      float bv = bvec[nt * 16 + c];
      acc[nt][0] += bv; acc[nt][1] += bv; acc[nt][2] += bv; acc[nt][3] += bv;
    }
    // row norms (row r = q*4+reg across 16 lanes of quad q)
#pragma unroll
    for (int r = 0; r < 4; r++) {
      float s = acc[0][r]*acc[0][r] + acc[1][r]*acc[1][r] + acc[2][r]*acc[2][r] + acc[3][r]*acc[3][r];
      s += __shfl_xor(s, 1); s += __shfl_xor(s, 2); s += __shfl_xor(s, 4); s += __shfl_xor(s, 8);
      float invn = 1.0f / fmaxf(sqrtf(s), 1e-12f);
      if (c == 0) invn_s[q * 4 + r] = invn;
    }
#pragma unroll
    for (int nt = 0; nt < 4; nt++)
#pragma unroll
      for (int r = 0; r < 4; r++)
        clu_s[(q * 4 + r) * 72 + nt * 16 + c] = f2bf(acc[nt][r]);
  } else {
    // ---- pass1 (waves 1-3): per-row d2-min partials, 16 rows x 12 ragged chunks
    int u = tid - 64;
    int row = u & 15, g = u >> 4;                    // g in [0,12)
    int col0 = (g < 8) ? g * 21 : 168 + (g - 8) * 22;
    int cw   = (g < 8) ? 21 : 22;
    int4 rm = clu_coords4[tile * 16 + row];
    float rbf = (float)rm.x;
    float x = (float)rm.y, y = (float)rm.z, z = (float)rm.w;
    float d2min = 3.4e38f;
    for (int i = 0; i < cw; i++) {
      float4 cm = cmeta[col0 + i];
      if (cm.x == rbf) {
        float dx = x - cm.y, dy = y - cm.z, dz = z - cm.w;
        d2min = fminf(d2min, dx*dx + dy*dy + dz*dz);  // min over d2 == min over d
      }
    }
    part_s[row][g] = d2min;
  }
  __syncthreads();  // B1

  if (tid < 16) {
    float m = 3.4e38f;
#pragma unroll
    for (int g = 0; g < 12; g++) m = fminf(m, part_s[tid][g]);
    dmin_s[tid] = fmaxf(sqrtf(m), 0.1f);  // empty batch -> huge sentinel (never matched)
  }
  __syncthreads();  // B2

  {
    // ---- pass2 (all 256): w = exp(dmin - d) once per (row,col); sum partials
    int row = tid & 15, ch = tid >> 4;
    int4 rm = clu_coords4[tile * 16 + row];
    float rbf = (float)rm.x;
    float x = (float)rm.y, y = (float)rm.z, z = (float)rm.w;
    float dmin = dmin_s[row];
    float ssum = 0.f;
    int base = row * WP + ch * 16;
    for (int i = 0; i < 16; i++) {
      float4 cm = cmeta[ch * 16 + i];
      float e = 0.f;
      if (cm.x == rbf) {
        float dx = x - cm.y, dy = y - cm.z, dz = z - cm.w;
        float d = fmaxf(sqrtf(dx*dx + dy*dy + dz*dz), 0.1f);
        e = __expf(dmin - d);   // arg <= 0 for matched cols by construction
      }
      w_s[base + i] = e;
      ssum += e;
    }
    part_s[row][ch] = ssum;
  }
  __syncthreads();  // B3

  if (tid < 16) {
    float s = 0.f;
#pragma unroll
    for (int ch = 0; ch < 16; ch++) s += part_s[tid][ch];
    float inv = (s > 0.f) ? 1.f / s : 0.f;
    scale_s[tid] = inv * invn_s[tid];
  }
  __syncthreads();  // B4

  {
    // ---- GEMM2 epilogue: each wave does 4 m-tiles; val overwrites w_s in place
    const uint4* cb = (const uint4*)clu_s;
    U16x8 a0, a1;
    a0.u = cb[c * 9 + q];       // k = 0..31
    a1.u = cb[c * 9 + 4 + q];   // k = 32..63
    float scl[4];
#pragma unroll
    for (int r = 0; r < 4; r++) scl[r] = scale_s[q * 4 + r];
    const uint4* cenb = (const uint4*)cen_ws;
#pragma unroll
    for (int i = 0; i < 4; i++) {
      int mt = wave * 4 + i;
      U16x8 b0, b1;
      b0.u = cenb[(mt * 16 + c) * 8 + q];
      b1.u = cenb[(mt * 16 + c) * 8 + 4 + q];
      f32x4 dacc = {0, 0, 0, 0};
      dacc = __builtin_amdgcn_mfma_f32_16x16x32_bf16(a0.v, b0.v, dacc, 0, 0, 0);
      dacc = __builtin_amdgcn_mfma_f32_16x16x32_bf16(a1.v, b1.v, dacc, 0, 0, 0);
      int m = mt * 16 + c;
#pragma unroll
      for (int r = 0; r < 4; r++) {
        int idx = (q * 4 + r) * WP + m;
        w_s[idx] = dacc[r] * w_s[idx] * scl[r];  // batch mask already in w (=0)
      }
    }
  }
  __syncthreads();  // B5

  {
    // ---- coalesced store: 1 KB per wave-instruction
    size_t obase = (size_t)tile * (16 * MM);
#pragma unroll
    for (int i = 0; i < 4; i++) {
      int j = i * 256 + tid;            // float4 id in 16x256 tile
      int row = j >> 6, col4 = j & 63;
      float4 v = *(const float4*)&w_s[row * WP + col4 * 4];
      *(float4*)(out + obase + (size_t)row * MM + col4 * 4) = v;
    }
  }
}

extern "C" void kernel_launch(void* const* d_in, const int* in_sizes, int n_in,
                              void* d_out, int out_size, void* d_ws, size_t ws_size,
                              hipStream_t stream) {
  const int* clu_coords = (const int*)d_in[0];
  const int* cen_coords = (const int*)d_in[1];
  const float* clu_feats = (const float*)d_in[2];
  const float* cen_feats = (const float*)d_in[3];
  const float* conf      = (const float*)d_in[4];
  const float* W         = (const float*)d_in[5];
  const float* bvec      = (const float*)d_in[6];
  float* out = (float*)d_out;

  char* ws = (char*)d_ws;
  unsigned short* cen_ws = (unsigned short*)ws;              // 32768 B
  unsigned short* wt_ws  = (unsigned short*)(ws + 32768);    // 16384 B
  float4* cmeta_ws       = (float4*)(ws + 32768 + 16384);    // 4096 B

  prep_kernel<<<17, 256, 0, stream>>>(cen_coords, cen_feats, conf, W, bvec,
                                      cen_ws, wt_ws, cmeta_ws);
  main_kernel<<<NTILES, 256, 0, stream>>>(
      (const int4*)clu_coords, clu_feats, bvec, cen_ws, wt_ws, cmeta_ws, out);
}

// Round 7
// 198.721 us; speedup vs baseline: 1.1961x; 1.1961x over previous
//
#include <hip/hip_runtime.h>
#include <stdint.h>

// InstanceHead on MI355X — f32/int32 inputs, f32 OUTPUT buffer.
// N=100000, M=256, B=8, L=128, D=64.  Batch ids UNSORTED (jnp.sort axis=-1 on
// (N,1) is a no-op).  out = (normalize(feats@W+b) @ (conf*(cen@W+b))^T) * attn.
// R7: wave-autonomous (1 wave = 1 16-row tile, ONE barrier total), attn
// weights live in 64 VGPRs per lane (each lane computes exactly the 64
// (row,col) dists its epilogue C-fragment needs — zero redundancy, zero
// LDS stats traffic).  Invalid cols encoded as d=1e30 -> exp()=0.

#define NN 100000
#define MM 256
#define LL 128
#define DD 64
#define NTILES (NN / 16)  // 6250, exact

typedef float f32x4 __attribute__((ext_vector_type(4)));
typedef __bf16 bf16x8 __attribute__((ext_vector_type(8)));

union U16x8 { uint4 u; bf16x8 v; unsigned short s[8]; };

static __device__ __forceinline__ unsigned short f2bf(float f) {
  union { float f; unsigned int i; } t; t.f = f;
  unsigned int x = t.i;
  x += 0x7fffu + ((x >> 16) & 1u);  // round-to-nearest-even
  return (unsigned short)(x >> 16);
}

// ---------------- prep: cen (bf16), W^T (bf16), centroid meta ----------------
__global__ __launch_bounds__(256) void prep_kernel(
    const int* __restrict__ cen_coords,
    const float* __restrict__ cen_feats,
    const float* __restrict__ conf,
    const float* __restrict__ W,
    const float* __restrict__ bvec,
    unsigned short* __restrict__ cen_ws,   // [256][64] bf16
    unsigned short* __restrict__ wt_ws,    // [64][128] bf16 (W transposed)
    float4* __restrict__ cmeta_ws)         // [256] {batch, x, y, z}
{
  int tid = threadIdx.x;
  if (blockIdx.x < 16) {
    int m = blockIdx.x * 16 + (tid >> 4);
    int c = tid & 15;
    float a0 = 0.f, a1 = 0.f, a2 = 0.f, a3 = 0.f;
    for (int l = 0; l < LL; l++) {
      float f = cen_feats[m * LL + l];
      const float* wr = W + l * DD + c;
      a0 += f * wr[0];  a1 += f * wr[16];
      a2 += f * wr[32]; a3 += f * wr[48];
    }
    float cf = conf[m];
    cen_ws[m * DD + c +  0] = f2bf(cf * (a0 + bvec[c +  0]));
    cen_ws[m * DD + c + 16] = f2bf(cf * (a1 + bvec[c + 16]));
    cen_ws[m * DD + c + 32] = f2bf(cf * (a2 + bvec[c + 32]));
    cen_ws[m * DD + c + 48] = f2bf(cf * (a3 + bvec[c + 48]));
  } else {
    for (int i = tid; i < LL * DD; i += 256) {
      int l = i >> 6, d = i & 63;
      wt_ws[d * LL + l] = f2bf(W[l * DD + d]);
    }
    {
      int4 cc = ((const int4*)cen_coords)[tid];  // tid < 256 == MM
      float4 f; f.x = (float)cc.x; f.y = (float)cc.y; f.z = (float)cc.z; f.w = (float)cc.w;
      cmeta_ws[tid] = f;
    }
  }
}

// ---------------- main: 1 wave per 16-row tile, one barrier ----------------
__global__ __launch_bounds__(256) void main_kernel(
    const int4* __restrict__ clu_coords4,
    const float* __restrict__ feats,
    const float* __restrict__ bvec,
    const unsigned short* __restrict__ cen_ws,
    const unsigned short* __restrict__ wt_ws,
    const float4* __restrict__ cmeta,
    float* __restrict__ out)
{
  __shared__ __align__(16) unsigned short clu_s[4][16 * 72];  // wave-private slices

  int tid = threadIdx.x;
  int wave = tid >> 6, lane = tid & 63;
  int q = lane >> 4, c = lane & 15;
  int tile = blockIdx.x * 4 + wave;
  bool live = tile < NTILES;

  float inv_nrm[4];
  if (live) {
    // ---- GEMM1: clu = feats @ W (+b).  A from global f32 feats (cvt->bf16),
    //      B from ws bf16 W^T (cache-resident).
    f32x4 acc[4] = {{0,0,0,0},{0,0,0,0},{0,0,0,0},{0,0,0,0}};
    const float4* fb = (const float4*)(feats + (size_t)(tile * 16 + c) * LL);
    const uint4* wb = (const uint4*)wt_ws;
#pragma unroll
    for (int ks = 0; ks < 4; ks++) {
      float4 f0 = fb[ks * 8 + q * 2];
      float4 f1 = fb[ks * 8 + q * 2 + 1];
      U16x8 a;
      a.s[0] = f2bf(f0.x); a.s[1] = f2bf(f0.y); a.s[2] = f2bf(f0.z); a.s[3] = f2bf(f0.w);
      a.s[4] = f2bf(f1.x); a.s[5] = f2bf(f1.y); a.s[6] = f2bf(f1.z); a.s[7] = f2bf(f1.w);
#pragma unroll
      for (int nt = 0; nt < 4; nt++) {
        U16x8 b; b.u = wb[(nt * 16 + c) * 16 + ks * 4 + q];
        acc[nt] = __builtin_amdgcn_mfma_f32_16x16x32_bf16(a.v, b.v, acc[nt], 0, 0, 0);
      }
    }
#pragma unroll
    for (int nt = 0; nt < 4; nt++) {
      float bv = bvec[nt * 16 + c];
      acc[nt][0] += bv; acc[nt][1] += bv; acc[nt][2] += bv; acc[nt][3] += bv;
    }
    // ---- row L2 norms (row r = q*4+reg lives across the 16 lanes of quad q)
#pragma unroll
    for (int r = 0; r < 4; r++) {
      float s = acc[0][r]*acc[0][r] + acc[1][r]*acc[1][r] + acc[2][r]*acc[2][r] + acc[3][r]*acc[3][r];
      s += __shfl_xor(s, 1); s += __shfl_xor(s, 2); s += __shfl_xor(s, 4); s += __shfl_xor(s, 8);
      inv_nrm[r] = 1.0f / fmaxf(sqrtf(s), 1e-12f);
    }
    // ---- clu tile -> LDS (bf16); norm folded into epilogue scale
#pragma unroll
    for (int nt = 0; nt < 4; nt++)
#pragma unroll
      for (int r = 0; r < 4; r++)
        clu_s[wave][(q * 4 + r) * 72 + nt * 16 + c] = f2bf(acc[nt][r]);
  }
  __syncthreads();  // the ONLY barrier (clu_s write -> A-frag read)
  if (!live) return;

  // ---- row meta for this lane's 4 C-rows
  int rb[4]; float rx[4], ry[4], rz[4];
#pragma unroll
  for (int r = 0; r < 4; r++) {
    int4 rm = clu_coords4[tile * 16 + q * 4 + r];
    rb[r] = rm.x; rx[r] = (float)rm.y; ry[r] = (float)rm.z; rz[r] = (float)rm.w;
  }

  // ---- pass A: this lane's 64 dists (col = mt*16+c, row = q*4+r), once each.
  //      invalid (cross-batch) -> 1e30 so exp() kills it later.
  float dv[16][4];
  float dmin[4] = {1e30f, 1e30f, 1e30f, 1e30f};
#pragma unroll
  for (int mt = 0; mt < 16; mt++) {
    float4 cm = cmeta[mt * 16 + c];
    int cbatch = (int)cm.x;
#pragma unroll
    for (int r = 0; r < 4; r++) {
      float dx = rx[r] - cm.y, dy = ry[r] - cm.z, dz = rz[r] - cm.w;
      float d = fmaxf(sqrtf(dx*dx + dy*dy + dz*dz), 0.1f);
      d = (cbatch == rb[r]) ? d : 1e30f;
      dv[mt][r] = d;
      dmin[r] = fminf(dmin[r], d);
    }
  }
  // ---- dmin over the row's 16 lanes; clamp so empty rows output exact 0
#pragma unroll
  for (int r = 0; r < 4; r++) {
    dmin[r] = fminf(dmin[r], __shfl_xor(dmin[r], 1));
    dmin[r] = fminf(dmin[r], __shfl_xor(dmin[r], 2));
    dmin[r] = fminf(dmin[r], __shfl_xor(dmin[r], 4));
    dmin[r] = fminf(dmin[r], __shfl_xor(dmin[r], 8));
    dmin[r] = fminf(dmin[r], 1e29f);
  }
  // ---- pass B: e = exp(dmin - d) in place; row sums
  float rsum[4] = {0.f, 0.f, 0.f, 0.f};
#pragma unroll
  for (int mt = 0; mt < 16; mt++)
#pragma unroll
    for (int r = 0; r < 4; r++) {
      float e = __expf(fminf(dmin[r] - dv[mt][r], 0.f));
      dv[mt][r] = e;
      rsum[r] += e;
    }
  float scale[4];
#pragma unroll
  for (int r = 0; r < 4; r++) {
    rsum[r] += __shfl_xor(rsum[r], 1);
    rsum[r] += __shfl_xor(rsum[r], 2);
    rsum[r] += __shfl_xor(rsum[r], 4);
    rsum[r] += __shfl_xor(rsum[r], 8);
    scale[r] = (rsum[r] > 0.f) ? inv_nrm[r] / rsum[r] : 0.f;
  }

  // ---- GEMM2 A-frags from LDS (unchanged since the barrier)
  const uint4* cb = (const uint4*)(clu_s[wave]);
  U16x8 a0, a1;
  a0.u = cb[c * 9 + q];       // k = 0..31
  a1.u = cb[c * 9 + 4 + q];   // k = 32..63

  const uint4* cenb = (const uint4*)cen_ws;
  size_t orow = (size_t)(tile * 16) * MM;
#pragma unroll
  for (int mt = 0; mt < 16; mt++) {
    U16x8 b0, b1;
    b0.u = cenb[(mt * 16 + c) * 8 + q];
    b1.u = cenb[(mt * 16 + c) * 8 + 4 + q];
    f32x4 dacc = {0, 0, 0, 0};
    dacc = __builtin_amdgcn_mfma_f32_16x16x32_bf16(a0.v, b0.v, dacc, 0, 0, 0);
    dacc = __builtin_amdgcn_mfma_f32_16x16x32_bf16(a1.v, b1.v, dacc, 0, 0, 0);
    int m = mt * 16 + c;
#pragma unroll
    for (int r = 0; r < 4; r++)
      out[orow + (size_t)(q * 4 + r) * MM + m] = dacc[r] * dv[mt][r] * scale[r];
  }
}

extern "C" void kernel_launch(void* const* d_in, const int* in_sizes, int n_in,
                              void* d_out, int out_size, void* d_ws, size_t ws_size,
                              hipStream_t stream) {
  const int* clu_coords = (const int*)d_in[0];
  const int* cen_coords = (const int*)d_in[1];
  const float* clu_feats = (const float*)d_in[2];
  const float* cen_feats = (const float*)d_in[3];
  const float* conf      = (const float*)d_in[4];
  const float* W         = (const float*)d_in[5];
  const float* bvec      = (const float*)d_in[6];
  float* out = (float*)d_out;

  char* ws = (char*)d_ws;
  unsigned short* cen_ws = (unsigned short*)ws;              // 32768 B
  unsigned short* wt_ws  = (unsigned short*)(ws + 32768);    // 16384 B
  float4* cmeta_ws       = (float4*)(ws + 32768 + 16384);    // 4096 B

  prep_kernel<<<17, 256, 0, stream>>>(cen_coords, cen_feats, conf, W, bvec,
                                      cen_ws, wt_ws, cmeta_ws);
  main_kernel<<<(NTILES + 3) / 4, 256, 0, stream>>>(
      (const int4*)clu_coords, clu_feats, bvec, cen_ws, wt_ws, cmeta_ws, out);
}